// Round 1
// 385.654 us; speedup vs baseline: 1.1105x; 1.1105x over previous
//
#include <hip/hip_runtime.h>
#include <cstdint>

#define M_DIM 8192   // B*S = 4*2048
#define N_DIM 4096   // D_OUT
#define K_DIM 4096   // D_IN
#define NT    32     // K_DIM / 128 K-tiles

typedef int i32x4 __attribute__((ext_vector_type(4)));

// async global->LDS, 16B per lane. LDS dest is wave-uniform base; HW
// scatters lane i to base + i*16. Global source IS per-lane (swizzle there).
__device__ __forceinline__ void gload_lds16(const void* g, void* l) {
  __builtin_amdgcn_global_load_lds(
      (const __attribute__((address_space(1))) unsigned int*)(uintptr_t)g,
      (__attribute__((address_space(3))) unsigned int*)(uintptr_t)l,
      16, 0, 0);
}

// ---------------- prep ----------------
// blocks [0,2048): x fp32 -> int8 per-row symmetric quant, ONE ROW PER WAVE
//   (no barriers, no LDS; shfl_xor reductions; bit-identical to old math).
// blocks [2048,3072): weight int32 (0..15) -> int8, grid-stride, dense loads.
__global__ __launch_bounds__(256) void prep_kernel(
    const float* __restrict__ x, const int* __restrict__ q,
    signed char* __restrict__ xq, signed char* __restrict__ wq8,
    float* __restrict__ sx, float* __restrict__ si) {
  const int tid  = threadIdx.x;
  const int lane = tid & 63;
  const int wv   = tid >> 6;
  if (blockIdx.x < 2048) {
    const int row = blockIdx.x * 4 + wv;
    const float* xr = x + (size_t)row * K_DIM;
    signed char* xo = xq + (size_t)row * K_DIM;
    float4 v[16];
    float amax = 0.f;
#pragma unroll
    for (int j = 0; j < 16; ++j) {
      v[j] = *(const float4*)(xr + j * 256 + lane * 4);
      amax = fmaxf(amax, fmaxf(fmaxf(fabsf(v[j].x), fabsf(v[j].y)),
                               fmaxf(fabsf(v[j].z), fabsf(v[j].w))));
    }
#pragma unroll
    for (int off = 32; off > 0; off >>= 1)
      amax = fmaxf(amax, __shfl_xor(amax, off, 64));
    const float inv = amax > 0.f ? 127.f / amax : 0.f;
    int isum = 0;
#pragma unroll
    for (int j = 0; j < 16; ++j) {
      int ix = __float2int_rn(v[j].x * inv);
      int iy = __float2int_rn(v[j].y * inv);
      int iz = __float2int_rn(v[j].z * inv);
      int iw = __float2int_rn(v[j].w * inv);
      isum += ix + iy + iz + iw;
      char4 o; o.x = (char)ix; o.y = (char)iy; o.z = (char)iz; o.w = (char)iw;
      *(char4*)(xo + j * 256 + lane * 4) = o;
    }
#pragma unroll
    for (int off = 32; off > 0; off >>= 1)
      isum += __shfl_xor(isum, off, 64);
    if (lane == 0) {
      sx[row] = amax * (1.f / 127.f);
      si[row] = (float)isum;
    }
  } else {
    const int bid = blockIdx.x - 2048;               // 0..1023
    const size_t total  = (size_t)N_DIM * K_DIM;     // 16.78M ints
    const size_t stride = (size_t)1024 * 4096;       // ints per sweep
    for (size_t base = (size_t)bid * 4096; base < total; base += stride) {
#pragma unroll
      for (int u = 0; u < 4; ++u) {
        const size_t idx = base + (size_t)u * 1024 + tid * 4;
        int4 w = *(const int4*)(q + idx);
        char4 o; o.x = (char)w.x; o.y = (char)w.y; o.z = (char)w.z; o.w = (char)w.w;
        *(char4*)(wq8 + idx) = o;
      }
    }
  }
}

// ---------------- GEMM i8, 256x256 tile, BK=128, 8 waves, 4-phase pipeline ----
// C[m,n] = sum_k xi[m,k]*q8[n,k] (i32 exact);
// epilogue: y = scale*sx[m]*(C - zp*si[m]) + bias[n]
//
// LDS: [buf][half][128 rows][128 B] for A and B (128 KiB total, dbuf).
// Rows are 128 B = 8 x 16B chunks; slot s of row r holds global chunk
// s ^ (r&7)  (XOR swizzle, both-sides: pre-swizzled global src for
// global_load_lds + swizzled ds_read addr; 0 extra bank conflicts).
// Schedule per K-tile t (buf = t&1), staging tile t+1 into buf^1:
//   ph1: vmcnt(2); stage B-half0; BAR; read A(mh0)+B(nh0); prio1; 16 MFMA; prio0
//   ph2:           stage B-half1; BAR; read B(nh1);        prio1; 16 MFMA; prio0
//   ph3: vmcnt(4); stage A-c0;    BAR; read A(mh1);        prio1; 16 MFMA; prio0
//   ph4:           stage A-c1;    BAR;                     prio1; 16 MFMA; prio0
// vmcnt never drains to 0 in steady state (counted waits, T4); buf^1's last
// reads finished at tile t-1 so stage-writes cannot clobber live reads.
__global__ __launch_bounds__(512) void qlinear_gemm_kernel(
    const signed char* __restrict__ A,     // [M][K] int8
    const signed char* __restrict__ Bm,    // [N][K] int8
    const float* __restrict__ sx,          // [M]
    const float* __restrict__ si,          // [M]
    const float* __restrict__ scale_p, const float* __restrict__ zp_p,
    const float* __restrict__ bias,        // [N]
    float* __restrict__ out) {             // [M][N] fp32
  __shared__ signed char sA[2][2][16384];  // 64 KB
  __shared__ signed char sB[2][2][16384];  // 64 KB

  const int tid  = threadIdx.x;
  const int lane = tid & 63;
  const int w    = tid >> 6;     // wave 0..7
  const int wr   = w >> 2;       // 0..1 : wave row (M), owns A-half wr
  const int wc   = w & 3;        // 0..3 : wave col (N)
  const int lr   = lane & 15;
  const int quad = lane >> 4;

  const int bm = blockIdx.y * 256;
  const int bn = blockIdx.x * 256;

  // ---- staging: per-lane pre-swizzled global source ----
  const int srow = lane >> 3;              // row within 8-row wave slab
  const int cg   = (lane & 7) ^ srow;      // global 16B chunk for this lane
  const signed char* aG = A  + (size_t)(bm + w * 8 + srow) * K_DIM + cg * 16;
  const signed char* bG = Bm + (size_t)(bn + w * 8 + srow) * K_DIM + cg * 16;
  const int dwoff = w * 1024;              // wave-uniform LDS slab offset

#define STG_A(dst, h, c, t) \
  gload_lds16(aG + (size_t)((h) * 128 + (c) * 64) * K_DIM + (size_t)(t) * 128, \
              (dst) + (h) * 16384 + (c) * 8192 + dwoff)
#define STG_B(dst, h, c, t) \
  gload_lds16(bG + (size_t)((h) * 128 + (c) * 64) * K_DIM + (size_t)(t) * 128, \
              (dst) + (h) * 16384 + (c) * 8192 + dwoff)

  // ---- read-side swizzled byte offsets (per k-substep) ----
  int off[2];
#pragma unroll
  for (int ks = 0; ks < 2; ++ks)
    off[ks] = lr * 128 + (((ks * 4 + quad) ^ (lr & 7)) * 16);

  i32x4 acc[8][4] = {};
  i32x4 afr[4][2];      // current mh's A fragments
  i32x4 bfr[2][2][2];   // [nh][n][ks] B fragments, live across the tile

  // ---- prologue: stage tile 0 in steady-state issue order ----
  {
    signed char* dA = &sA[0][0][0];
    signed char* dB = &sB[0][0][0];
    STG_B(dB, 0, 0, 0); STG_B(dB, 0, 1, 0);
    STG_B(dB, 1, 0, 0); STG_B(dB, 1, 1, 0);
    STG_A(dA, 0, 0, 0); STG_A(dA, 1, 0, 0);
    STG_A(dA, 0, 1, 0); STG_A(dA, 1, 1, 0);
  }

  for (int t = 0; t < NT; ++t) {
    const int buf = t & 1;
    const signed char* pA = &sA[buf][wr][0];
    const signed char* pB = &sB[buf][wc >> 1][0] + (wc & 1) * 8192;
    signed char* nA = &sA[buf ^ 1][0][0];
    signed char* nB = &sB[buf ^ 1][0][0];
    const bool st = (t + 1) < NT;
    const int tn = t + 1;

    // ---------- phase 1 : Q00 (mh=0, nh=0) ----------
    asm volatile("s_waitcnt vmcnt(2)" ::: "memory");  // tile t: B all + A-c0 landed
    if (st) { STG_B(nB, 0, 0, tn); STG_B(nB, 0, 1, tn); }
    __builtin_amdgcn_s_barrier();
#pragma unroll
    for (int m = 0; m < 4; ++m)
#pragma unroll
      for (int ks = 0; ks < 2; ++ks)
        afr[m][ks] = *(const i32x4*)(pA + m * 2048 + off[ks]);
#pragma unroll
    for (int n = 0; n < 2; ++n)
#pragma unroll
      for (int ks = 0; ks < 2; ++ks)
        bfr[0][n][ks] = *(const i32x4*)(pB + n * 2048 + off[ks]);
    __builtin_amdgcn_s_setprio(1);
#pragma unroll
    for (int m = 0; m < 4; ++m)
#pragma unroll
      for (int n = 0; n < 2; ++n)
#pragma unroll
        for (int ks = 0; ks < 2; ++ks)
          acc[m][n] = __builtin_amdgcn_mfma_i32_16x16x64_i8(
              afr[m][ks], bfr[0][n][ks], acc[m][n], 0, 0, 0);
    __builtin_amdgcn_s_setprio(0);

    // ---------- phase 2 : Q01 (mh=0, nh=1) ----------
    if (st) { STG_B(nB, 1, 0, tn); STG_B(nB, 1, 1, tn); }
    __builtin_amdgcn_s_barrier();
#pragma unroll
    for (int n = 0; n < 2; ++n)
#pragma unroll
      for (int ks = 0; ks < 2; ++ks)
        bfr[1][n][ks] = *(const i32x4*)(pB + 4096 + n * 2048 + off[ks]);
    __builtin_amdgcn_s_setprio(1);
#pragma unroll
    for (int m = 0; m < 4; ++m)
#pragma unroll
      for (int n = 0; n < 2; ++n)
#pragma unroll
        for (int ks = 0; ks < 2; ++ks)
          acc[m][2 + n] = __builtin_amdgcn_mfma_i32_16x16x64_i8(
              afr[m][ks], bfr[1][n][ks], acc[m][2 + n], 0, 0, 0);
    __builtin_amdgcn_s_setprio(0);

    // ---------- phase 3 : Q10 (mh=1, nh=0) ----------
    if (st) asm volatile("s_waitcnt vmcnt(4)" ::: "memory");  // tile t: A-c1 landed
    else    asm volatile("s_waitcnt vmcnt(0)" ::: "memory");  // last tile drain
    if (st) { STG_A(nA, 0, 0, tn); STG_A(nA, 1, 0, tn); }
    __builtin_amdgcn_s_barrier();
#pragma unroll
    for (int m = 0; m < 4; ++m)
#pragma unroll
      for (int ks = 0; ks < 2; ++ks)
        afr[m][ks] = *(const i32x4*)(pA + 8192 + m * 2048 + off[ks]);
    __builtin_amdgcn_s_setprio(1);
#pragma unroll
    for (int m = 0; m < 4; ++m)
#pragma unroll
      for (int n = 0; n < 2; ++n)
#pragma unroll
        for (int ks = 0; ks < 2; ++ks)
          acc[4 + m][n] = __builtin_amdgcn_mfma_i32_16x16x64_i8(
              afr[m][ks], bfr[0][n][ks], acc[4 + m][n], 0, 0, 0);
    __builtin_amdgcn_s_setprio(0);

    // ---------- phase 4 : Q11 (mh=1, nh=1) ----------
    if (st) { STG_A(nA, 0, 1, tn); STG_A(nA, 1, 1, tn); }
    __builtin_amdgcn_s_barrier();
    __builtin_amdgcn_s_setprio(1);
#pragma unroll
    for (int m = 0; m < 4; ++m)
#pragma unroll
      for (int n = 0; n < 2; ++n)
#pragma unroll
        for (int ks = 0; ks < 2; ++ks)
          acc[4 + m][2 + n] = __builtin_amdgcn_mfma_i32_16x16x64_i8(
              afr[m][ks], bfr[1][n][ks], acc[4 + m][2 + n], 0, 0, 0);
    __builtin_amdgcn_s_setprio(0);
  }
#undef STG_A
#undef STG_B

  // ---------- epilogue ----------
  const float scale = *scale_p;
  const float zp    = *zp_p;
  // C/D layout: col = lane&15, row = quad*4 + reg (dtype-independent)
#pragma unroll
  for (int i = 0; i < 8; ++i) {
    const int gm0 = bm + wr * 128 + i * 16 + quad * 4;
    float am[4], cm[4];
#pragma unroll
    for (int r = 0; r < 4; ++r) {
      am[r] = scale * sx[gm0 + r];
      cm[r] = -am[r] * zp * si[gm0 + r];
    }
#pragma unroll
    for (int j = 0; j < 4; ++j) {
      const int gn = bn + wc * 64 + j * 16 + lr;
      const float bb = bias[gn];
#pragma unroll
      for (int r = 0; r < 4; ++r)
        out[(size_t)(gm0 + r) * N_DIM + gn] =
            am[r] * (float)acc[i][j][r] + cm[r] + bb;
    }
  }
}

extern "C" void kernel_launch(void* const* d_in, const int* in_sizes, int n_in,
                              void* d_out, int out_size, void* d_ws, size_t ws_size,
                              hipStream_t stream) {
  const float* x     = (const float*)d_in[0];
  const int*   wq    = (const int*)d_in[1];
  const float* scale = (const float*)d_in[2];
  const float* zp    = (const float*)d_in[3];
  const float* bias  = (const float*)d_in[4];
  float* out = (float*)d_out;

  // ws: xq (8192*4096 i8) | wq8 (4096*4096 i8) | sx | si
  signed char* xq  = (signed char*)d_ws;
  signed char* wq8 = xq + (size_t)M_DIM * K_DIM;
  float* sx = (float*)(wq8 + (size_t)N_DIM * K_DIM);
  float* si = sx + M_DIM;

  prep_kernel<<<3072, 256, 0, stream>>>(x, wq, xq, wq8, sx, si);
  dim3 grid(N_DIM / 256, M_DIM / 256);  // 16 x 32
  qlinear_gemm_kernel<<<grid, 512, 0, stream>>>(xq, wq8, sx, si, scale, zp, bias, out);
}

// Round 2
// 385.510 us; speedup vs baseline: 1.1110x; 1.0004x over previous
//
#include <hip/hip_runtime.h>
#include <cstdint>

#define M_DIM 8192   // B*S = 4*2048
#define N_DIM 4096   // D_OUT
#define K_DIM 4096   // D_IN
#define NT    32     // K_DIM / 128 K-tiles

typedef int i32x4 __attribute__((ext_vector_type(4)));

// async global->LDS, 16B per lane. LDS dest is wave-uniform base; HW
// scatters lane i to base + i*16. Global source IS per-lane (swizzle there).
__device__ __forceinline__ void gload_lds16(const void* g, void* l) {
  __builtin_amdgcn_global_load_lds(
      (const __attribute__((address_space(1))) unsigned int*)(uintptr_t)g,
      (__attribute__((address_space(3))) unsigned int*)(uintptr_t)l,
      16, 0, 0);
}

// ---------------- prep (unchanged from r1) ----------------
__global__ __launch_bounds__(256) void prep_kernel(
    const float* __restrict__ x, const int* __restrict__ q,
    signed char* __restrict__ xq, signed char* __restrict__ wq8,
    float* __restrict__ sx, float* __restrict__ si) {
  const int tid  = threadIdx.x;
  const int lane = tid & 63;
  const int wv   = tid >> 6;
  if (blockIdx.x < 2048) {
    const int row = blockIdx.x * 4 + wv;
    const float* xr = x + (size_t)row * K_DIM;
    signed char* xo = xq + (size_t)row * K_DIM;
    float4 v[16];
    float amax = 0.f;
#pragma unroll
    for (int j = 0; j < 16; ++j) {
      v[j] = *(const float4*)(xr + j * 256 + lane * 4);
      amax = fmaxf(amax, fmaxf(fmaxf(fabsf(v[j].x), fabsf(v[j].y)),
                               fmaxf(fabsf(v[j].z), fabsf(v[j].w))));
    }
#pragma unroll
    for (int off = 32; off > 0; off >>= 1)
      amax = fmaxf(amax, __shfl_xor(amax, off, 64));
    const float inv = amax > 0.f ? 127.f / amax : 0.f;
    int isum = 0;
#pragma unroll
    for (int j = 0; j < 16; ++j) {
      int ix = __float2int_rn(v[j].x * inv);
      int iy = __float2int_rn(v[j].y * inv);
      int iz = __float2int_rn(v[j].z * inv);
      int iw = __float2int_rn(v[j].w * inv);
      isum += ix + iy + iz + iw;
      char4 o; o.x = (char)ix; o.y = (char)iy; o.z = (char)iz; o.w = (char)iw;
      *(char4*)(xo + j * 256 + lane * 4) = o;
    }
#pragma unroll
    for (int off = 32; off > 0; off >>= 1)
      isum += __shfl_xor(isum, off, 64);
    if (lane == 0) {
      sx[row] = amax * (1.f / 127.f);
      si[row] = (float)isum;
    }
  } else {
    const int bid = blockIdx.x - 2048;               // 0..1023
    const size_t total  = (size_t)N_DIM * K_DIM;     // 16.78M ints
    const size_t stride = (size_t)1024 * 4096;       // ints per sweep
    for (size_t base = (size_t)bid * 4096; base < total; base += stride) {
#pragma unroll
      for (int u = 0; u < 4; ++u) {
        const size_t idx = base + (size_t)u * 1024 + tid * 4;
        int4 w = *(const int4*)(q + idx);
        char4 o; o.x = (char)w.x; o.y = (char)w.y; o.z = (char)w.z; o.w = (char)w.w;
        *(char4*)(wq8 + idx) = o;
      }
    }
  }
}

// ---------------- GEMM i8, 256x256 tile, BK=128, 8 waves ----------------
// 2-region schedule per K-tile (2 barriers, was 4), counted lgkmcnt so the
// ks1 ds_reads fly under the ks0 MFMA cluster, counted vmcnt (never 0 in
// steady state), XCD-chunked block swizzle.
//
// Per-wave vmcnt ledger (loads for tile t+1 issued during tile t):
//   enter region1(t): 8 outstanding (tile t's loads) -> vmcnt(2): B*4+A-c0*2
//     landed; BAR collectivizes; stage B*4 (t+1) -> <=6 outstanding
//   enter region2(t): vmcnt(4): A-c1*2 of t landed (4 newest = B of t+1);
//     BAR; stage A-c0*2, A-c1*2 (t+1) -> <=8 outstanding
// Stage-into-buf^1 happens only after region1's BAR, which every wave reaches
// only after its lgkmcnt(0) delivered the last buf^1 reads (region2 of t-1).
__global__ __launch_bounds__(512) void qlinear_gemm_kernel(
    const signed char* __restrict__ A,     // [M][K] int8
    const signed char* __restrict__ Bm,    // [N][K] int8
    const float* __restrict__ sx,          // [M]
    const float* __restrict__ si,          // [M]
    const float* __restrict__ scale_p, const float* __restrict__ zp_p,
    const float* __restrict__ bias,        // [N]
    float* __restrict__ out) {             // [M][N] fp32
  __shared__ signed char sA[2][2][16384];  // 64 KB
  __shared__ signed char sB[2][2][16384];  // 64 KB

  const int tid  = threadIdx.x;
  const int lane = tid & 63;
  const int w    = tid >> 6;     // wave 0..7
  const int wr   = w >> 2;       // 0..1 : wave row (M), owns A-half wr
  const int wc   = w & 3;        // 0..3 : wave col (N)
  const int lr   = lane & 15;
  const int quad = lane >> 4;

  // XCD-chunked swizzle (bijective: 512 % 8 == 0). Each XCD owns 64
  // consecutive swz ids = 4 full M-rows of blocks -> A panels stay in its L2.
  const int bid = blockIdx.x;                  // 0..511
  const int swz = (bid & 7) * 64 + (bid >> 3);
  const int bm  = (swz >> 4) * 256;            // 32 M-rows
  const int bn  = (swz & 15) * 256;            // 16 N-cols

  // ---- staging: per-lane pre-swizzled global source ----
  const int srow = lane >> 3;              // row within 8-row wave slab
  const int cg   = (lane & 7) ^ srow;      // global 16B chunk for this lane
  const signed char* aG = A  + (size_t)(bm + w * 8 + srow) * K_DIM + cg * 16;
  const signed char* bG = Bm + (size_t)(bn + w * 8 + srow) * K_DIM + cg * 16;
  const int dwoff = w * 1024;              // wave-uniform LDS slab offset

#define STG_A(dst, h, c, t) \
  gload_lds16(aG + (size_t)((h) * 128 + (c) * 64) * K_DIM + (size_t)(t) * 128, \
              (dst) + (h) * 16384 + (c) * 8192 + dwoff)
#define STG_B(dst, h, c, t) \
  gload_lds16(bG + (size_t)((h) * 128 + (c) * 64) * K_DIM + (size_t)(t) * 128, \
              (dst) + (h) * 16384 + (c) * 8192 + dwoff)

  // read-side swizzled byte offsets per k-substep (row%8 == lr%8 here)
  int off[2];
#pragma unroll
  for (int ks = 0; ks < 2; ++ks)
    off[ks] = lr * 128 + (((ks * 4 + quad) ^ (lr & 7)) * 16);

  i32x4 acc[8][4] = {};
  i32x4 afr[4][2];      // current m-half's A fragments [msub][ks]
  i32x4 bfr[4][2];      // B fragments [nsub][ks], live across the tile

  // ---- prologue: stage tile 0, oldest-first order = B*4, A-c0*2, A-c1*2 ----
  {
    signed char* dA = &sA[0][0][0];
    signed char* dB = &sB[0][0][0];
    STG_B(dB, 0, 0, 0); STG_B(dB, 0, 1, 0);
    STG_B(dB, 1, 0, 0); STG_B(dB, 1, 1, 0);
    STG_A(dA, 0, 0, 0); STG_A(dA, 1, 0, 0);
    STG_A(dA, 0, 1, 0); STG_A(dA, 1, 1, 0);
  }

  for (int t = 0; t < NT; ++t) {
    const int buf = t & 1;
    const signed char* pA = &sA[buf][wr][0];
    const signed char* pB = &sB[buf][wc >> 1][0] + (wc & 1) * 8192;
    signed char* nA = &sA[buf ^ 1][0][0];
    signed char* nB = &sB[buf ^ 1][0][0];
    const bool st = (t + 1) < NT;
    const int tn = t + 1;

    // ================= region 1 : m-subtiles 0..3 (rows 0..63 = A-c0) ======
    asm volatile("s_waitcnt vmcnt(2)" ::: "memory");   // B*4 + A-c0*2 landed
    __builtin_amdgcn_s_barrier();
    if (st) { STG_B(nB, 0, 0, tn); STG_B(nB, 0, 1, tn);
              STG_B(nB, 1, 0, tn); STG_B(nB, 1, 1, tn); }
    // reads: ks0 group first (order-pinned), then ks1 group
#pragma unroll
    for (int m = 0; m < 4; ++m)
      afr[m][0] = *(const i32x4*)(pA + m * 2048 + off[0]);
#pragma unroll
    for (int n = 0; n < 4; ++n)
      bfr[n][0] = *(const i32x4*)(pB + n * 2048 + off[0]);
    __builtin_amdgcn_sched_barrier(0);
#pragma unroll
    for (int m = 0; m < 4; ++m)
      afr[m][1] = *(const i32x4*)(pA + m * 2048 + off[1]);
#pragma unroll
    for (int n = 0; n < 4; ++n)
      bfr[n][1] = *(const i32x4*)(pB + n * 2048 + off[1]);
    __builtin_amdgcn_sched_barrier(0);
    asm volatile("s_waitcnt lgkmcnt(8)" ::: "memory"); // ks0 frags delivered
    __builtin_amdgcn_sched_barrier(0);
    __builtin_amdgcn_s_setprio(1);
#pragma unroll
    for (int m = 0; m < 4; ++m)
#pragma unroll
      for (int n = 0; n < 4; ++n)
        acc[m][n] = __builtin_amdgcn_mfma_i32_16x16x64_i8(
            afr[m][0], bfr[n][0], acc[m][n], 0, 0, 0);
    __builtin_amdgcn_s_setprio(0);
    asm volatile("s_waitcnt lgkmcnt(0)" ::: "memory"); // ks1 frags delivered
    __builtin_amdgcn_sched_barrier(0);
    __builtin_amdgcn_s_setprio(1);
#pragma unroll
    for (int m = 0; m < 4; ++m)
#pragma unroll
      for (int n = 0; n < 4; ++n)
        acc[m][n] = __builtin_amdgcn_mfma_i32_16x16x64_i8(
            afr[m][1], bfr[n][1], acc[m][n], 0, 0, 0);
    __builtin_amdgcn_s_setprio(0);

    // ================= region 2 : m-subtiles 4..7 (rows 64..127 = A-c1) ====
    if (st) asm volatile("s_waitcnt vmcnt(4)" ::: "memory");  // A-c1 of t landed
    else    asm volatile("s_waitcnt vmcnt(0)" ::: "memory");  // last tile drain
    __builtin_amdgcn_s_barrier();
    if (st) { STG_A(nA, 0, 0, tn); STG_A(nA, 1, 0, tn);
              STG_A(nA, 0, 1, tn); STG_A(nA, 1, 1, tn); }
#pragma unroll
    for (int m = 0; m < 4; ++m)
      afr[m][0] = *(const i32x4*)(pA + 8192 + m * 2048 + off[0]);
    __builtin_amdgcn_sched_barrier(0);
#pragma unroll
    for (int m = 0; m < 4; ++m)
      afr[m][1] = *(const i32x4*)(pA + 8192 + m * 2048 + off[1]);
    __builtin_amdgcn_sched_barrier(0);
    asm volatile("s_waitcnt lgkmcnt(4)" ::: "memory"); // ks0 A frags delivered
    __builtin_amdgcn_sched_barrier(0);
    __builtin_amdgcn_s_setprio(1);
#pragma unroll
    for (int m = 0; m < 4; ++m)
#pragma unroll
      for (int n = 0; n < 4; ++n)
        acc[4 + m][n] = __builtin_amdgcn_mfma_i32_16x16x64_i8(
            afr[m][0], bfr[n][0], acc[4 + m][n], 0, 0, 0);
    __builtin_amdgcn_s_setprio(0);
    asm volatile("s_waitcnt lgkmcnt(0)" ::: "memory");
    __builtin_amdgcn_sched_barrier(0);
    __builtin_amdgcn_s_setprio(1);
#pragma unroll
    for (int m = 0; m < 4; ++m)
#pragma unroll
      for (int n = 0; n < 4; ++n)
        acc[4 + m][n] = __builtin_amdgcn_mfma_i32_16x16x64_i8(
            afr[m][1], bfr[n][1], acc[4 + m][n], 0, 0, 0);
    __builtin_amdgcn_s_setprio(0);
  }
#undef STG_A
#undef STG_B

  // ---------- epilogue ----------
  const float scale = *scale_p;
  const float zp    = *zp_p;
  // C/D layout: col = lane&15, row = quad*4 + reg (dtype-independent)
#pragma unroll
  for (int i = 0; i < 8; ++i) {
    const int gm0 = bm + wr * 128 + i * 16 + quad * 4;
    float am[4], cm[4];
#pragma unroll
    for (int r = 0; r < 4; ++r) {
      am[r] = scale * sx[gm0 + r];
      cm[r] = -am[r] * zp * si[gm0 + r];
    }
#pragma unroll
    for (int j = 0; j < 4; ++j) {
      const int gn = bn + wc * 64 + j * 16 + lr;
      const float bb = bias[gn];
#pragma unroll
      for (int r = 0; r < 4; ++r)
        out[(size_t)(gm0 + r) * N_DIM + gn] =
            am[r] * (float)acc[i][j][r] + cm[r] + bb;
    }
  }
}

extern "C" void kernel_launch(void* const* d_in, const int* in_sizes, int n_in,
                              void* d_out, int out_size, void* d_ws, size_t ws_size,
                              hipStream_t stream) {
  const float* x     = (const float*)d_in[0];
  const int*   wq    = (const int*)d_in[1];
  const float* scale = (const float*)d_in[2];
  const float* zp    = (const float*)d_in[3];
  const float* bias  = (const float*)d_in[4];
  float* out = (float*)d_out;

  // ws: xq (8192*4096 i8) | wq8 (4096*4096 i8) | sx | si
  signed char* xq  = (signed char*)d_ws;
  signed char* wq8 = xq + (size_t)M_DIM * K_DIM;
  float* sx = (float*)(wq8 + (size_t)N_DIM * K_DIM);
  float* si = sx + M_DIM;

  prep_kernel<<<3072, 256, 0, stream>>>(x, wq, xq, wq8, sx, si);
  qlinear_gemm_kernel<<<512, 512, 0, stream>>>(xq, wq8, sx, si, scale, zp, bias, out);
}